// Round 4
// baseline (1283.649 us; speedup 1.0000x reference)
//
#include <hip/hip_runtime.h>

#define NT 131072
#define ED 256
#define NE 512
#define LDSTRIDE 132   // 128 floats payload + 4 pad -> bank shift 4/row, 2-way max
#define TPB 128        // tokens per block

// ---------------------------------------------------------------------------
// K0: ee[c] = sum_k emb[c][k]^2   (512 codes, one wave per code)
// ---------------------------------------------------------------------------
__global__ __launch_bounds__(64) void vq_ee_kernel(const float* __restrict__ emb,
                                                   float* __restrict__ ee) {
  const int c = blockIdx.x;
  const int l = threadIdx.x;
  float4 v = *reinterpret_cast<const float4*>(emb + (size_t)c * ED + l * 4);
  float s = v.x * v.x + v.y * v.y + v.z * v.z + v.w * v.w;
#pragma unroll
  for (int m = 32; m; m >>= 1) s += __shfl_xor(s, m, 64);
  if (l == 0) ee[c] = s;
}

// ---------------------------------------------------------------------------
// K1: per-token argmin over 512 codes + min-dist^2 sum + noise^2 sum + hist.
// Block = 256 threads (4 waves), 128 tokens/block, 8x4 micro-tile per thread.
// Each LDS-read emb float feeds 8 FMAs so LDS-pipe time (~164 us in the
// pessimistic delivered-bytes model) stays under the fp32 FMA floor (218 us)
// and hides behind VALU (separate pipes). Codes in 8 chunks of 64, each
// staged in two k-halves of 128 -> padded LDS tile [64][132] = 33 KB.
// __launch_bounds__(256,4): VGPR<=128 (live ~100) -> 4 blocks/CU, and
// grid 1024 = 256 CUs x 4 -> single resident round, zero tail.
// Thread (tg = tid>>4, tx = tid&15): tokens {tok0+tg+16i, i<8},
// codes {c0+tx+16j, j<4}. LDS read bank start (4*tx + k) % 32 -> 2-way (free),
// affine in k. z fragments from global: 16 lanes/address -> 64 B distinct per
// wave-load, L1/L2-resident (~1 GB total, trivial).
// ---------------------------------------------------------------------------
__global__ __launch_bounds__(256, 4) void vq_main_kernel(
    const float* __restrict__ z, const float* __restrict__ emb,
    const float* __restrict__ noise, const float* __restrict__ ee,
    float* __restrict__ idx_out, float* __restrict__ hist,
    double* __restrict__ sums) {
  __shared__ float es[64 * LDSTRIDE];
  __shared__ float red[4];

  const int tid = threadIdx.x;
  const int lane = tid & 63;
  const int wave = tid >> 6;
  const int tx = tid & 15;
  const int tg = tid >> 4;
  const size_t tok0 = (size_t)blockIdx.x * TPB;

  // ---- fused noise^2 partial sum (this block's slice of noise) ----
  float nacc = 0.f;
  {
    const float4* n4 = reinterpret_cast<const float4*>(noise);
    const size_t base = (size_t)blockIdx.x * 8192 + tid;
#pragma unroll 4
    for (int it = 0; it < 32; ++it) {
      float4 v = n4[base + (size_t)it * 256];
      nacc += v.x * v.x + v.y * v.y + v.z * v.z + v.w * v.w;
    }
  }
#pragma unroll
  for (int m = 32; m; m >>= 1) nacc += __shfl_xor(nacc, m, 64);
  if (lane == 0) red[wave] = nacc;
  __syncthreads();
  if (tid == 0) atomicAdd(&sums[1], (double)(red[0] + red[1] + red[2] + red[3]));

  const float* zb = z + (tok0 + tg) * ED;  // token row base (i stride 16*ED)
  const float* esp = es + tx * LDSTRIDE;

  float mv[8];
  int mi[8];
#pragma unroll
  for (int i = 0; i < 8; ++i) { mv[i] = 3.4e38f; mi[i] = 0; }

  for (int ch = 0; ch < 8; ++ch) {
    const int c0 = ch * 64;
    float eev[4];
#pragma unroll
    for (int j = 0; j < 4; ++j) eev[j] = ee[c0 + tx + 16 * j];

    float acc[8][4];
#pragma unroll
    for (int i = 0; i < 8; ++i)
#pragma unroll
      for (int j = 0; j < 4; ++j) acc[i][j] = 0.f;

#pragma unroll
    for (int h = 0; h < 2; ++h) {
      __syncthreads();  // previous half's reads done before overwrite
      // stage 64 codes x 128 k-floats: 2048 float4, 8 per thread
#pragma unroll
      for (int it = 0; it < 8; ++it) {
        const int flat = it * 256 + tid;     // float4 slot
        const int r = flat >> 5;             // code row 0..63
        const int q = flat & 31;             // quad within half-row
        float4 v = *reinterpret_cast<const float4*>(
            emb + (size_t)(c0 + r) * ED + h * 128 + q * 4);
        *reinterpret_cast<float4*>(es + r * LDSTRIDE + q * 4) = v;
      }
      __syncthreads();

      const float* zh = zb + h * 128;
#pragma unroll 2
      for (int k = 0; k < 128; k += 4) {
        float4 ef[4];
#pragma unroll
        for (int j = 0; j < 4; ++j)
          ef[j] = *reinterpret_cast<const float4*>(esp + j * (16 * LDSTRIDE) + k);
#pragma unroll
        for (int i = 0; i < 8; ++i) {
          float4 zf = *reinterpret_cast<const float4*>(zh + i * (16 * ED) + k);
#pragma unroll
          for (int j = 0; j < 4; ++j) {
            acc[i][j] = fmaf(zf.x, ef[j].x, acc[i][j]);
            acc[i][j] = fmaf(zf.y, ef[j].y, acc[i][j]);
            acc[i][j] = fmaf(zf.z, ef[j].z, acc[i][j]);
            acc[i][j] = fmaf(zf.w, ef[j].w, acc[i][j]);
          }
        }
      }
    }

    // running (min, argmin); codes ascend with (ch, j); strict '<' keeps the
    // first occurrence, matching jnp.argmin tie-break.
#pragma unroll
    for (int j = 0; j < 4; ++j) {
      const int c = c0 + tx + 16 * j;
#pragma unroll
      for (int i = 0; i < 8; ++i) {
        const float sim = eev[j] - 2.f * acc[i][j];
        if (sim < mv[i]) { mv[i] = sim; mi[i] = c; }
      }
    }
  }

  // ---- zz[t] = sum_k z[t][k]^2, 16 owner lanes each sum 16 elements ----
  float zz[8];
#pragma unroll
  for (int i = 0; i < 8; ++i) {
    const float* row = z + (tok0 + tg + 16 * i) * ED + tx * 16;
    float s = 0.f;
#pragma unroll
    for (int m = 0; m < 4; ++m) {
      float4 v = *reinterpret_cast<const float4*>(row + 4 * m);
      s = fmaf(v.x, v.x, s);
      s = fmaf(v.y, v.y, s);
      s = fmaf(v.z, v.z, s);
      s = fmaf(v.w, v.w, s);
    }
    zz[i] = s;
  }

  // ---- reduce (min, argmin, zz-sum) across the 16 lanes per token ----
#pragma unroll
  for (int s = 1; s < 16; s <<= 1) {
#pragma unroll
    for (int i = 0; i < 8; ++i) {
      const float ov = __shfl_xor(mv[i], s, 16);
      const int oi = __shfl_xor(mi[i], s, 16);
      const float oz = __shfl_xor(zz[i], s, 16);
      zz[i] += oz;
      if (ov < mv[i] || (ov == mv[i] && oi < mi[i])) { mv[i] = ov; mi[i] = oi; }
    }
  }

  float d4 = 0.f;
  if (tx == 0) {
#pragma unroll
    for (int i = 0; i < 8; ++i) {
      const size_t t = tok0 + tg + 16 * i;
      idx_out[t] = (float)mi[i];
      atomicAdd(&hist[mi[i]], 1.0f);
      d4 += zz[i] + mv[i];  // dist^2 = ||z||^2 + (ee - 2*z.e)_min
    }
  }
#pragma unroll
  for (int m = 32; m; m >>= 1) d4 += __shfl_xor(d4, m, 64);
  if (lane == 0) red[wave] = d4;
  __syncthreads();
  if (tid == 0) atomicAdd(&sums[0], (double)(red[0] + red[1] + red[2] + red[3]));
}

// ---------------------------------------------------------------------------
// K2: z_q = z + scale * noise; scale = sqrt(dist2_sum / noise2_sum) computed
// per block from the finalized sums (stream ordering guarantees K1 done).
// ---------------------------------------------------------------------------
__global__ __launch_bounds__(256) void vq_out_kernel(const float* __restrict__ z,
                                                     const float* __restrict__ noise,
                                                     const double* __restrict__ sums,
                                                     float* __restrict__ out) {
  __shared__ float sh_s;
  if (threadIdx.x == 0) sh_s = (float)sqrt(sums[0] / sums[1]);
  __syncthreads();
  const float s = sh_s;
  const float4* z4 = reinterpret_cast<const float4*>(z);
  const float4* n4 = reinterpret_cast<const float4*>(noise);
  float4* o4 = reinterpret_cast<float4*>(out);
  const size_t base = (size_t)blockIdx.x * 4096 + threadIdx.x;
#pragma unroll
  for (int it = 0; it < 16; ++it) {
    const size_t i = base + (size_t)it * 256;
    float4 a = z4[i];
    float4 n = n4[i];
    float4 r;
    r.x = fmaf(s, n.x, a.x);
    r.y = fmaf(s, n.y, a.y);
    r.z = fmaf(s, n.z, a.z);
    r.w = fmaf(s, n.w, a.w);
    o4[i] = r;
  }
}

extern "C" void kernel_launch(void* const* d_in, const int* in_sizes, int n_in,
                              void* d_out, int out_size, void* d_ws, size_t ws_size,
                              hipStream_t stream) {
  (void)in_sizes; (void)n_in; (void)out_size; (void)ws_size;
  const float* z = (const float*)d_in[0];
  const float* emb = (const float*)d_in[1];
  const float* noise = (const float*)d_in[2];
  const float* hist_in = (const float*)d_in[3];

  float* out = (float*)d_out;
  float* zq_out = out;                              // [NT*ED]
  float* idx_out = out + (size_t)NT * ED;           // [NT]
  float* hist_out = idx_out + NT;                   // [NE]

  // ws layout: [0..15] two doubles (dist2_sum, noise2_sum); [64..] ee[512].
  double* sums = (double*)d_ws;
  float* ee = (float*)((char*)d_ws + 64);

  hipMemsetAsync(d_ws, 0, 16, stream);
  hipMemcpyAsync(hist_out, hist_in, NE * sizeof(float),
                 hipMemcpyDeviceToDevice, stream);

  vq_ee_kernel<<<NE, 64, 0, stream>>>(emb, ee);
  vq_main_kernel<<<NT / TPB, 256, 0, stream>>>(z, emb, noise, ee, idx_out,
                                               hist_out, sums);
  vq_out_kernel<<<(size_t)NT * ED / 4 / 4096, 256, 0, stream>>>(z, noise, sums,
                                                                zq_out);
}

// Round 12
// 1207.485 us; speedup vs baseline: 1.0631x; 1.0631x over previous
//
#include <hip/hip_runtime.h>

#define NT 131072
#define ED 256
#define NE 512
#define LDSTRIDE 132   // 128 floats payload + 4 pad -> bank shift 4/row, 2-way max
#define TPB 128        // tokens per block

// ---------------------------------------------------------------------------
// K0: ee[c] = sum_k emb[c][k]^2   (512 codes, one wave per code)
// ---------------------------------------------------------------------------
__global__ __launch_bounds__(64) void vq_ee_kernel(const float* __restrict__ emb,
                                                   float* __restrict__ ee) {
  const int c = blockIdx.x;
  const int l = threadIdx.x;
  float4 v = *reinterpret_cast<const float4*>(emb + (size_t)c * ED + l * 4);
  float s = v.x * v.x + v.y * v.y + v.z * v.z + v.w * v.w;
#pragma unroll
  for (int m = 32; m; m >>= 1) s += __shfl_xor(s, m, 64);
  if (l == 0) ee[c] = s;
}

// ---------------------------------------------------------------------------
// K1: per-token argmin over 512 codes + min-dist^2 sum + noise^2 sum + hist.
// Block = 256 threads (4 waves), 128 tokens/block, 8x4 micro-tile per thread.
// NO VGPR cap: round-4's __launch_bounds__(256,4) forced a 64-VGPR budget ->
// ~3.4 KB/thread scratch spills (WRITE_SIZE 893 MB) -> 1070 us. ~102 live
// regs, compiler free to take ~110-128 -> no spills, 4 blocks/CU by LDS.
// zz (||z||^2 per token) folded into chunk 0's k-loop (z already in regs),
// removing the tail z re-read; all 16 tx lanes hold identical zz sums.
// ---------------------------------------------------------------------------
__global__ __launch_bounds__(256) void vq_main_kernel(
    const float* __restrict__ z, const float* __restrict__ emb,
    const float* __restrict__ noise, const float* __restrict__ ee,
    float* __restrict__ idx_out, float* __restrict__ hist,
    double* __restrict__ sums) {
  __shared__ float es[64 * LDSTRIDE];
  __shared__ float red[4];

  const int tid = threadIdx.x;
  const int lane = tid & 63;
  const int wave = tid >> 6;
  const int tx = tid & 15;
  const int tg = tid >> 4;
  const size_t tok0 = (size_t)blockIdx.x * TPB;

  // ---- fused noise^2 partial sum (this block's slice of noise) ----
  float nacc = 0.f;
  {
    const float4* n4 = reinterpret_cast<const float4*>(noise);
    const size_t base = (size_t)blockIdx.x * 8192 + tid;
#pragma unroll 4
    for (int it = 0; it < 32; ++it) {
      float4 v = n4[base + (size_t)it * 256];
      nacc += v.x * v.x + v.y * v.y + v.z * v.z + v.w * v.w;
    }
  }
#pragma unroll
  for (int m = 32; m; m >>= 1) nacc += __shfl_xor(nacc, m, 64);
  if (lane == 0) red[wave] = nacc;
  __syncthreads();
  if (tid == 0) atomicAdd(&sums[1], (double)(red[0] + red[1] + red[2] + red[3]));

  const float* zb = z + (tok0 + tg) * ED;  // token row base (i stride 16*ED)
  const float* esp = es + tx * LDSTRIDE;

  float mv[8];
  int mi[8];
  float zz[8];
#pragma unroll
  for (int i = 0; i < 8; ++i) { mv[i] = 3.4e38f; mi[i] = 0; zz[i] = 0.f; }

  // One pass over a 64-code chunk: stage emb in two k-halves, accumulate
  // 8x4 dot products, fold into running (min, argmin). with_zz=true also
  // accumulates zz[i] = ||z_token_i||^2 (only for the first chunk).
  auto chunk_pass = [&](const int c0, const bool with_zz) {
    float eev[4];
#pragma unroll
    for (int j = 0; j < 4; ++j) eev[j] = ee[c0 + tx + 16 * j];

    float acc[8][4];
#pragma unroll
    for (int i = 0; i < 8; ++i)
#pragma unroll
      for (int j = 0; j < 4; ++j) acc[i][j] = 0.f;

#pragma unroll
    for (int h = 0; h < 2; ++h) {
      __syncthreads();  // previous half's reads done before overwrite
      // stage 64 codes x 128 k-floats: 2048 float4, 8 per thread
#pragma unroll
      for (int it = 0; it < 8; ++it) {
        const int flat = it * 256 + tid;     // float4 slot
        const int r = flat >> 5;             // code row 0..63
        const int q = flat & 31;             // quad within half-row
        float4 v = *reinterpret_cast<const float4*>(
            emb + (size_t)(c0 + r) * ED + h * 128 + q * 4);
        *reinterpret_cast<float4*>(es + r * LDSTRIDE + q * 4) = v;
      }
      __syncthreads();

      const float* zh = zb + h * 128;
#pragma unroll 2
      for (int k = 0; k < 128; k += 4) {
        float4 ef[4];
#pragma unroll
        for (int j = 0; j < 4; ++j)
          ef[j] = *reinterpret_cast<const float4*>(esp + j * (16 * LDSTRIDE) + k);
#pragma unroll
        for (int i = 0; i < 8; ++i) {
          float4 zf = *reinterpret_cast<const float4*>(zh + i * (16 * ED) + k);
#pragma unroll
          for (int j = 0; j < 4; ++j) {
            acc[i][j] = fmaf(zf.x, ef[j].x, acc[i][j]);
            acc[i][j] = fmaf(zf.y, ef[j].y, acc[i][j]);
            acc[i][j] = fmaf(zf.z, ef[j].z, acc[i][j]);
            acc[i][j] = fmaf(zf.w, ef[j].w, acc[i][j]);
          }
          if (with_zz) {
            zz[i] = fmaf(zf.x, zf.x, zz[i]);
            zz[i] = fmaf(zf.y, zf.y, zz[i]);
            zz[i] = fmaf(zf.z, zf.z, zz[i]);
            zz[i] = fmaf(zf.w, zf.w, zz[i]);
          }
        }
      }
    }

    // running (min, argmin); codes ascend with (c0, j); strict '<' keeps the
    // first occurrence, matching jnp.argmin tie-break.
#pragma unroll
    for (int j = 0; j < 4; ++j) {
      const int c = c0 + tx + 16 * j;
#pragma unroll
      for (int i = 0; i < 8; ++i) {
        const float sim = eev[j] - 2.f * acc[i][j];
        if (sim < mv[i]) { mv[i] = sim; mi[i] = c; }
      }
    }
  };

  chunk_pass(0, true);
  for (int ch = 1; ch < 8; ++ch) chunk_pass(ch * 64, false);

  // ---- reduce (min, argmin) across the 16 lanes per token ----
  // zz needs no reduce: every tx lane computed the identical full-k sum.
#pragma unroll
  for (int s = 1; s < 16; s <<= 1) {
#pragma unroll
    for (int i = 0; i < 8; ++i) {
      const float ov = __shfl_xor(mv[i], s, 16);
      const int oi = __shfl_xor(mi[i], s, 16);
      if (ov < mv[i] || (ov == mv[i] && oi < mi[i])) { mv[i] = ov; mi[i] = oi; }
    }
  }

  float d4 = 0.f;
  if (tx == 0) {
#pragma unroll
    for (int i = 0; i < 8; ++i) {
      const size_t t = tok0 + tg + 16 * i;
      idx_out[t] = (float)mi[i];
      atomicAdd(&hist[mi[i]], 1.0f);
      d4 += zz[i] + mv[i];  // dist^2 = ||z||^2 + (ee - 2*z.e)_min
    }
  }
#pragma unroll
  for (int m = 32; m; m >>= 1) d4 += __shfl_xor(d4, m, 64);
  if (lane == 0) red[wave] = d4;
  __syncthreads();
  if (tid == 0) atomicAdd(&sums[0], (double)(red[0] + red[1] + red[2] + red[3]));
}

// ---------------------------------------------------------------------------
// K2: z_q = z + scale * noise; scale = sqrt(dist2_sum / noise2_sum) computed
// per block from the finalized sums (stream ordering guarantees K1 done).
// ---------------------------------------------------------------------------
__global__ __launch_bounds__(256) void vq_out_kernel(const float* __restrict__ z,
                                                     const float* __restrict__ noise,
                                                     const double* __restrict__ sums,
                                                     float* __restrict__ out) {
  __shared__ float sh_s;
  if (threadIdx.x == 0) sh_s = (float)sqrt(sums[0] / sums[1]);
  __syncthreads();
  const float s = sh_s;
  const float4* z4 = reinterpret_cast<const float4*>(z);
  const float4* n4 = reinterpret_cast<const float4*>(noise);
  float4* o4 = reinterpret_cast<float4*>(out);
  const size_t base = (size_t)blockIdx.x * 4096 + threadIdx.x;
#pragma unroll
  for (int it = 0; it < 16; ++it) {
    const size_t i = base + (size_t)it * 256;
    float4 a = z4[i];
    float4 n = n4[i];
    float4 r;
    r.x = fmaf(s, n.x, a.x);
    r.y = fmaf(s, n.y, a.y);
    r.z = fmaf(s, n.z, a.z);
    r.w = fmaf(s, n.w, a.w);
    o4[i] = r;
  }
}

extern "C" void kernel_launch(void* const* d_in, const int* in_sizes, int n_in,
                              void* d_out, int out_size, void* d_ws, size_t ws_size,
                              hipStream_t stream) {
  (void)in_sizes; (void)n_in; (void)out_size; (void)ws_size;
  const float* z = (const float*)d_in[0];
  const float* emb = (const float*)d_in[1];
  const float* noise = (const float*)d_in[2];
  const float* hist_in = (const float*)d_in[3];

  float* out = (float*)d_out;
  float* zq_out = out;                              // [NT*ED]
  float* idx_out = out + (size_t)NT * ED;           // [NT]
  float* hist_out = idx_out + NT;                   // [NE]

  // ws layout: [0..15] two doubles (dist2_sum, noise2_sum); [64..] ee[512].
  double* sums = (double*)d_ws;
  float* ee = (float*)((char*)d_ws + 64);

  hipMemsetAsync(d_ws, 0, 16, stream);
  hipMemcpyAsync(hist_out, hist_in, NE * sizeof(float),
                 hipMemcpyDeviceToDevice, stream);

  vq_ee_kernel<<<NE, 64, 0, stream>>>(emb, ee);
  vq_main_kernel<<<NT / TPB, 256, 0, stream>>>(z, emb, noise, ee, idx_out,
                                               hist_out, sums);
  vq_out_kernel<<<(size_t)NT * ED / 4 / 4096, 256, 0, stream>>>(z, noise, sums,
                                                                zq_out);
}